// Round 7
// baseline (731.645 us; speedup 1.0000x reference)
//
// R7 = R6 resubmitted byte-identical (R6 hit "container failed twice" with no
// profile; audit found no deadlock/OOB vector and R3->R4 precedent says flake).
#include <hip/hip_runtime.h>

#define NXI 384
#define NG  (NXI*NXI)          // 147456 elements per system
#define NSYS 8
#define BPS 32                 // blocks per system
#define NBLK (NSYS*BPS)        // 256 blocks
#define NTHR 512               // proven geometry: 128 VGPR, no spill
#define ROWS_PB 12             // rows per block
#define EPB (ROWS_PB*NXI)      // 4608 elements per block
#define EPT (EPB/NTHR)         // 9 elements per thread
#define SIDX(r) (((r)+2)*NXI)  // slabP/slabR index, rows -2..13 (16 rows)
#define VIDX(r) (((r)+3)*NXI)  // slabV index, rows -3..14 (18 rows; restart x-staging)

// thr = EPS*NX*NY = 1e-9*147456
#define THRC 1.47456e-4f

// ---- relaxed agent-scope accessors ----
__device__ __forceinline__ float aloadf(const float* p) {
  return __hip_atomic_load(p, __ATOMIC_RELAXED, __HIP_MEMORY_SCOPE_AGENT);
}
__device__ __forceinline__ void astoref(float* p, float v) {
  __hip_atomic_store(p, v, __ATOMIC_RELAXED, __HIP_MEMORY_SCOPE_AGENT);
}
__device__ __forceinline__ double aloadd(const double* p) {
  return __hip_atomic_load(p, __ATOMIC_RELAXED, __HIP_MEMORY_SCOPE_AGENT);
}
__device__ __forceinline__ void astored(double* p, double v) {
  __hip_atomic_store(p, v, __ATOMIC_RELAXED, __HIP_MEMORY_SCOPE_AGENT);
}

__device__ __forceinline__ double wave_red(double v) {
#pragma unroll
  for (int off = 32; off > 0; off >>= 1) v += __shfl_down(v, off, 64);
  return v;
}

// ---- per-system flag barrier: contention-free, no RMW (validated r7-r11) ----
__device__ __forceinline__ void sys_bar(unsigned* flags, unsigned* phase, int tid, int bs) {
  __atomic_signal_fence(__ATOMIC_SEQ_CST);
  __builtin_amdgcn_s_waitcnt(0);
  __syncthreads();
  const unsigned ph = ++(*phase);
  if (tid == 0) {
    __hip_atomic_store(flags + bs, ph, __ATOMIC_RELAXED, __HIP_MEMORY_SCOPE_AGENT);
  }
  if (tid < 64) {
    while (true) {
      const unsigned f = __hip_atomic_load(flags + (tid & 31), __ATOMIC_RELAXED,
                                           __HIP_MEMORY_SCOPE_AGENT);
      if (__ballot(f >= ph) == ~0ull) break;
      __builtin_amdgcn_s_sleep(1);
    }
  }
  __syncthreads();
  __atomic_signal_fence(__ATOMIC_SEQ_CST);
}

// Block-reduce n<=9 doubles, agent-store to channels [chan0..][sys][bs].
__device__ __forceinline__ void bredN(const double* v, int n,
                                      double* slots, int chan0,
                                      int sys, int bs, int tid) {
  __shared__ double sred[NTHR/64][9];
  const int wid = tid >> 6, lane = tid & 63;
#pragma unroll
  for (int q = 0; q < n; q++) {
    const double w = wave_red(v[q]);
    if (lane == 0) sred[wid][q] = w;
  }
  __syncthreads();
  if (tid == 0) {
#pragma unroll
    for (int q = 0; q < n; q++) {
      double a = 0.0;
#pragma unroll
      for (int w2 = 0; w2 < NTHR/64; w2++) a += sred[w2][q];
      astored(slots + (size_t)(chan0 + q) * NBLK + sys * BPS + bs, a);
    }
  }
  __syncthreads();
}

// Butterfly sums of n channels over 32 slots (bit-exact in every lane/block).
__device__ __forceinline__ void shredN(const double* slots, int chan0, int n,
                                       int sys, int lane, double* out) {
  double v[14];
#pragma unroll
  for (int q = 0; q < n; q++)
    v[q] = aloadd(slots + (size_t)(chan0 + q) * NBLK + sys * BPS + (lane & 31));
#pragma unroll
  for (int q = 0; q < n; q++) {
    double x = v[q];
    x += __shfl_xor(x, 1, 64);
    x += __shfl_xor(x, 2, 64);
    x += __shfl_xor(x, 4, 64);
    x += __shfl_xor(x, 8, 64);
    x += __shfl_xor(x, 16, 64);
    out[q] = x;
  }
}

__device__ __forceinline__ float froguard(double sq) {
  return sq > 0.0 ? (float)sqrt(sq) : 0.0f;
}

// 5 stencil coefficients at global (row i, col j). 0=boo 1=bmo 2=bom 3=bop 4=bpo
__device__ __forceinline__ void coef5(const float* __restrict__ Vb,
                                      const float* __restrict__ M1b,
                                      const float* __restrict__ M2b,
                                      int i, int j, float* c5) {
  const int a0 = (i - 1 < 0) ? 0 : i - 1;
  const int a2 = (i + 1 > NXI - 1) ? NXI - 1 : i + 1;
  const int b0 = (j - 1 < 0) ? 0 : j - 1;
  const int b2 = (j + 1 > NXI - 1) ? NXI - 1 : j + 1;
  const float vc = Vb[j * NXI + i] + 1.0f;
  const float vu = Vb[j * NXI + a0] + 1.0f;
  const float vd = Vb[j * NXI + a2] + 1.0f;
  const float vl = Vb[b0 * NXI + i] + 1.0f;
  const float vr = Vb[b2 * NXI + i] + 1.0f;
  const float D1A = M1b[j * NXI + i] * ((vd - vc) / (0.5f * (vd + vc)));
  const float D1B = M1b[j * NXI + a0] * ((vc - vu) / (0.5f * (vc + vu)));
  const float D2A = M2b[j * NXI + i] * ((vr - vc) / (0.5f * (vr + vc)));
  const float D2B = M2b[b0 * NXI + i] * ((vc - vl) / (0.5f * (vc + vl)));
  c5[0] = 41.0f - 5.0f * (D1B - D1A) - 5.0f * (D2B - D2A);
  c5[1] = -10.0f - 5.0f * D1B;
  c5[2] = -10.0f - 5.0f * D2B;
  c5[3] = -10.0f + 5.0f * D2A;
  c5[4] = -10.0f + 5.0f * D1A;
}

__global__ __launch_bounds__(NTHR, 1) void bicg_kernel(
    const float* __restrict__ V, const float* __restrict__ M1, const float* __restrict__ M2,
    float* __restrict__ xout, float* __restrict__ wsf) {
  const int blk = blockIdx.x;
  const int sys = blk & (NSYS - 1);
  const int bs  = blk >> 3;
  const int tid = threadIdx.x;
  const int lane = tid & 63;
  const int gr0 = bs * ROWS_PB;

  // ---- LDS (~148 KB): v,u,w live in LDS so per-thread regs stay at 128 ----
  __shared__ float slabP[16 * NXI];   // p, rows -2..13 (halo-2, recursively maintained)
  __shared__ float slabR[16 * NXI];   // r, rows -2..13 (halo-2, recursively maintained)
  __shared__ float slabV[18 * NXI];   // v rows -1..12 (hot); x rows -3..14 (restart staging)
  __shared__ float slabU[12 * NXI];   // u = A r, own rows 0..11
  __shared__ float slabW[12 * NXI];   // w = A v, own rows 0..11
  __shared__ float cgh[2][5][NXI];    // coeffs at rows -1 (side 0) and 12 (side 1)
  __shared__ float ghV[4 * NXI];      // received v at rows -2,-1,12,13 (slots 0..3)
  __shared__ float ghU[4 * NXI];      // received u
  __shared__ float ghW[4 * NXI];      // received w
  __shared__ float bcf[4];            // 0:alpha 1:omega 2:beta 3:r_abs
  __shared__ int   bci[1];            // 0 normal, 1 RES, 2 C3, 3 converged-at-init
  __shared__ float sh_r0abs;

  // ---- workspace ----
  unsigned* flags = (unsigned*)wsf + sys * 32;               // memset 0 pre-launch
  double* slots = (double*)(wsf + 1024);                     // 16 chans * 256 doubles
  float* ghp_all = wsf + 16384;                              // [sys][bs][3 vec][4 rows][NXI]
  float* ghp_sys = ghp_all + (size_t)sys * (BPS * 12 * NXI);
  float* ghp_own = ghp_sys + (size_t)bs * (12 * NXI);
  float* ghx_all = ghp_all + (size_t)NSYS * BPS * 12 * NXI;  // [sys][bs][6 rows][NXI]
  float* ghx_sys = ghx_all + (size_t)sys * (BPS * 6 * NXI);
  float* ghx_own = ghx_sys + (size_t)bs * (6 * NXI);

  unsigned bphase = 0;

  const size_t so = (size_t)sys * NG;
  const float* Vb  = V  + so;
  const float* M1b = M1 + so;
  const float* M2b = M2 + so;
  float* xs = xout + so + (size_t)bs * EPB;

  // ---------- Phase 0: own coeffs -> regs; ghost-row coeffs -> cgh; V-mean ----------
  float cboo_r[EPT], cbmo_r[EPT], cbom_r[EPT], cbop_r[EPT], cbpo_r[EPT];
#pragma unroll
  for (int k = 0; k < EPT; k++) {
    const int e = tid + k * NTHR;
    const int lr = e / NXI, c = e - lr * NXI;
    float c5[5];
    coef5(Vb, M1b, M2b, gr0 + lr, c, c5);
    cboo_r[k] = c5[0]; cbmo_r[k] = c5[1]; cbom_r[k] = c5[2];
    cbop_r[k] = c5[3]; cbpo_r[k] = c5[4];
  }
  for (int g = tid; g < 2 * NXI; g += NTHR) {
    const bool top = g < NXI;
    if (top ? (bs > 0) : (bs < BPS - 1)) {
      const int c = top ? g : g - NXI;
      const int side = top ? 0 : 1;
      const int gi = top ? gr0 - 1 : gr0 + ROWS_PB;
      float c5[5];
      coef5(Vb, M1b, M2b, gi, c, c5);
      cgh[side][0][c] = c5[0]; cgh[side][1][c] = c5[1]; cgh[side][2][c] = c5[2];
      cgh[side][3][c] = c5[3]; cgh[side][4][c] = c5[4];
    }
  }
  {
    double vsum = 0.0;
#pragma unroll
    for (int k = 0; k < EPT; k++) vsum += (double)Vb[bs * EPB + tid + k * NTHR];
    bredN(&vsum, 1, slots, 14, sys, bs, tid);
  }
  sys_bar(flags, &bphase, tid, bs);  // S0

  // ---------- Init: x=mb; p=r=r0 = mb - rowsum*mb on own + halo-2 ghost rows ----------
  double smb[1]; shredN(slots, 14, 1, sys, lane, smb);
  const float mb = (float)(smb[0] / (double)NG) + 1.0f;
  float preg[EPT], rreg[EPT], r0reg[EPT], xreg[EPT];
#pragma unroll
  for (int k = 0; k < EPT; k++) {
    const int e = tid + k * NTHR;
    const int lr = e / NXI, c = e - lr * NXI;
    const float pn = mb - (cboo_r[k] + cbmo_r[k] + cbom_r[k] + cbop_r[k] + cbpo_r[k]) * mb;
    xreg[k] = mb;
    preg[k] = pn; rreg[k] = pn; r0reg[k] = pn;
    slabP[SIDX(lr) + c] = pn;
    slabR[SIDX(lr) + c] = pn;
  }
  for (int g = tid; g < 4 * NXI; g += NTHR) {
    const int slot = g / NXI, c = g - slot * NXI;
    if (slot < 2 ? (bs > 0) : (bs < BPS - 1)) {
      const int row = (slot == 0) ? -2 : (slot == 1) ? -1 : (slot == 2) ? ROWS_PB : ROWS_PB + 1;
      float c5[5];
      coef5(Vb, M1b, M2b, gr0 + row, c, c5);
      const float pn = mb - (c5[0] + c5[1] + c5[2] + c5[3] + c5[4]) * mb;
      slabP[SIDX(row) + c] = pn;
      slabR[SIDX(row) + c] = pn;
    }
  }
  if (tid == 0) { bcf[3] = 1.0f; bci[0] = 0; }

  for (int it = 0; it < 30; ++it) {
    __syncthreads();                 // slab/bcf writes visible
    if (!(bcf[3] > THRC)) break;     // uniform within system

    // ==== A: v = A p -> slabV (own rows + ghost rows -1/12); publish boundary v ====
#pragma unroll
    for (int k = 0; k < EPT; k++) {
      const int e = tid + k * NTHR;
      const int lr = e / NXI, c = e - lr * NXI;
      const int gr = gr0 + lr;
      const float uc = preg[k];
      const float um = (gr == 0)       ? uc : slabP[SIDX(lr - 1) + c];
      const float ud = (gr == NXI - 1) ? uc : slabP[SIDX(lr + 1) + c];
      const float ul = (c == 0)        ? uc : slabP[SIDX(lr) + c - 1];
      const float ur = (c == NXI - 1)  ? uc : slabP[SIDX(lr) + c + 1];
      const float vv = cboo_r[k] * uc + cbmo_r[k] * um + cbom_r[k] * ul + cbop_r[k] * ur + cbpo_r[k] * ud;
      slabV[VIDX(lr) + c] = vv;
      int slot = -1;
      if (lr == 0) slot = 0; else if (lr == 1) slot = 1;
      else if (lr == ROWS_PB - 2) slot = 2; else if (lr == ROWS_PB - 1) slot = 3;
      if (slot >= 0) astoref(ghp_own + (0 * 4 + slot) * NXI + c, vv);
    }
    for (int g = tid; g < 2 * NXI; g += NTHR) {
      const bool top = g < NXI;
      if (top ? (bs > 0) : (bs < BPS - 1)) {
        const int c = top ? g : g - NXI;
        const int row = top ? -1 : ROWS_PB;
        const int side = top ? 0 : 1;
        const float uc = slabP[SIDX(row) + c];
        const float um = slabP[SIDX(row - 1) + c];
        const float ud = slabP[SIDX(row + 1) + c];
        const float ul = (c == 0)       ? uc : slabP[SIDX(row) + c - 1];
        const float ur = (c == NXI - 1) ? uc : slabP[SIDX(row) + c + 1];
        slabV[VIDX(row) + c] = cgh[side][0][c] * uc + cgh[side][1][c] * um +
                               cgh[side][2][c] * ul + cgh[side][3][c] * ur + cgh[side][4][c] * ud;
      }
    }
    __syncthreads();

    // ==== B1: u = A r -> slabU; publish boundary u; 9 dots (chans 0..8) ====
    {
      double d1[9];
#pragma unroll
      for (int q = 0; q < 9; q++) d1[q] = 0.0;
#pragma unroll
      for (int k = 0; k < EPT; k++) {
        const int e = tid + k * NTHR;
        const int lr = e / NXI, c = e - lr * NXI;
        const int gr = gr0 + lr;
        const float rc = rreg[k];
        const float rum = (gr == 0)       ? rc : slabR[SIDX(lr - 1) + c];
        const float rud = (gr == NXI - 1) ? rc : slabR[SIDX(lr + 1) + c];
        const float rul = (c == 0)        ? rc : slabR[SIDX(lr) + c - 1];
        const float rur = (c == NXI - 1)  ? rc : slabR[SIDX(lr) + c + 1];
        const float uu_ = cboo_r[k] * rc + cbmo_r[k] * rum + cbom_r[k] * rul + cbop_r[k] * rur + cbpo_r[k] * rud;
        slabU[lr * NXI + c] = uu_;
        int slot = -1;
        if (lr == 0) slot = 0; else if (lr == 1) slot = 1;
        else if (lr == ROWS_PB - 2) slot = 2; else if (lr == ROWS_PB - 1) slot = 3;
        if (slot >= 0) astoref(ghp_own + (1 * 4 + slot) * NXI + c, uu_);
        const float vc = slabV[VIDX(lr) + c];
        const double dv = vc, du = uu_, dr = rc, dr0 = r0reg[k];
        d1[0] += dv * dr0;   // <v,r0>  sigma
        d1[1] += dv * dv;    // <v,v>
        d1[2] += dr * dr0;   // <r,r0>  rho
        d1[3] += dr * dv;    // <r,v>
        d1[4] += dr * dr;    // <r,r>
        d1[5] += du * du;    // <u,u>
        d1[6] += du * dr;    // <u,r>
        d1[7] += du * dv;    // <u,v>
        d1[8] += du * dr0;   // <u,r0>
      }
      bredN(d1, 9, slots, 0, sys, bs, tid);
    }
    // ==== B2: w = A v -> slabW; publish boundary w; 5 dots (chans 9..13) ====
    {
      double d2[5];
#pragma unroll
      for (int q = 0; q < 5; q++) d2[q] = 0.0;
#pragma unroll
      for (int k = 0; k < EPT; k++) {
        const int e = tid + k * NTHR;
        const int lr = e / NXI, c = e - lr * NXI;
        const int gr = gr0 + lr;
        const float vc = slabV[VIDX(lr) + c];
        const float vum = (gr == 0)       ? vc : slabV[VIDX(lr - 1) + c];
        const float vud = (gr == NXI - 1) ? vc : slabV[VIDX(lr + 1) + c];
        const float vul = (c == 0)        ? vc : slabV[VIDX(lr) + c - 1];
        const float vur = (c == NXI - 1)  ? vc : slabV[VIDX(lr) + c + 1];
        const float ww_ = cboo_r[k] * vc + cbmo_r[k] * vum + cbom_r[k] * vul + cbop_r[k] * vur + cbpo_r[k] * vud;
        slabW[lr * NXI + c] = ww_;
        int slot = -1;
        if (lr == 0) slot = 0; else if (lr == 1) slot = 1;
        else if (lr == ROWS_PB - 2) slot = 2; else if (lr == ROWS_PB - 1) slot = 3;
        if (slot >= 0) astoref(ghp_own + (2 * 4 + slot) * NXI + c, ww_);
        const float uu_ = slabU[lr * NXI + c];   // same-thread write in B1
        const double dww = ww_, du = uu_, dv = vc, dr = rreg[k], dr0 = r0reg[k];
        d2[0] += du * dww;   // <u,w>
        d2[1] += dww * dww;  // <w,w>
        d2[2] += dww * dr;   // <w,r>
        d2[3] += dww * dv;   // <w,v>
        d2[4] += dww * dr0;  // <w,r0>
      }
      bredN(d2, 5, slots, 9, sys, bs, tid);
    }
    sys_bar(flags, &bphase, tid, bs);  // THE single hot sync

    // ==== D: wave0 computes ALL scalars || other waves receive v,u,w ghosts ====
    if (tid < 64) {
      double s[14];
      shredN(slots, 0, 14, sys, lane, s);
      const float sigma = (float)s[0];
      const float v_abs = froguard(s[1]);
      const float rho_f = (float)s[2];
      const float r0a = (it == 0) ? froguard(s[4]) : sh_r0abs;
      int code = 0;
      float al = 0.f, om = 0.f, be = 0.f, ra = 0.f;
      if (it == 0 && !(r0a > THRC)) {
        code = 3; ra = r0a;
      } else if (sigma <= 1e-9f * v_abs * r0a) {
        code = 1;
      } else {
        al = rho_f / sigma;
        const double da = (double)al;
        const double ss2 = s[4] - 2.0 * da * s[3] + da * da * s[1];
        const float s_abs = froguard(ss2);
        if (s_abs <= THRC) {
          code = 2; ra = s_abs;
        } else {
          const double tt = s[5] - 2.0 * da * s[9] + da * da * s[10];
          const double ts = s[6] - da * s[7] - da * s[11] + da * da * s[12];
          om = (float)ts / (float)tt;
          const double dwv = (double)om;
          const double sr0 = s[2] - da * s[0];
          const double tr0 = s[8] - da * s[13];
          const float rho_new = (float)(sr0 - dwv * tr0);
          be = (al / om) * (rho_new / rho_f);
          const double rr_new = ss2 - 2.0 * dwv * ts + dwv * dwv * tt;
          ra = froguard(rr_new);
        }
      }
      if (lane == 0) {
        bci[0] = code; bcf[0] = al; bcf[1] = om; bcf[2] = be;
        if (code != 1) bcf[3] = ra;
        if (it == 0) sh_r0abs = r0a;
      }
    } else {
      for (int g = tid - 64; g < 4 * NXI; g += NTHR - 64) {
        const int slot = g / NXI, c = g - slot * NXI;
        if (slot < 2) {
          if (bs > 0) {
            const float* src = ghp_sys + (size_t)(bs - 1) * (12 * NXI);
            ghV[g] = aloadf(src + (0 * 4 + slot + 2) * NXI + c);
            ghU[g] = aloadf(src + (1 * 4 + slot + 2) * NXI + c);
            ghW[g] = aloadf(src + (2 * 4 + slot + 2) * NXI + c);
          }
        } else {
          if (bs < BPS - 1) {
            const float* src = ghp_sys + (size_t)(bs + 1) * (12 * NXI);
            ghV[g] = aloadf(src + (0 * 4 + slot - 2) * NXI + c);
            ghU[g] = aloadf(src + (1 * 4 + slot - 2) * NXI + c);
            ghW[g] = aloadf(src + (2 * 4 + slot - 2) * NXI + c);
          }
        }
      }
    }
    __syncthreads();
    const int code = bci[0];

    if (code == 3) continue;          // converged at init

    if (code == 1) {
      // ---- restart: p=r=r0 = mb - A x (3-row x exchange for halo-2 rebuild) ----
#pragma unroll
      for (int k = 0; k < EPT; k++) {
        const int e = tid + k * NTHR;
        const int lr = e / NXI, c = e - lr * NXI;
        slabV[VIDX(lr) + c] = xreg[k];
        if (lr <= 2)           astoref(ghx_own + lr * NXI + c, xreg[k]);
        if (lr >= ROWS_PB - 3) astoref(ghx_own + (lr - (ROWS_PB - 3) + 3) * NXI + c, xreg[k]);
      }
      sys_bar(flags, &bphase, tid, bs);  // R1
      for (int g = tid; g < 6 * NXI; g += NTHR) {
        const int slot = g / NXI, c = g - slot * NXI;
        if (slot < 3) {
          if (bs > 0)
            slabV[VIDX(slot - 3) + c] =
                aloadf(ghx_sys + (size_t)(bs - 1) * (6 * NXI) + (slot + 3) * NXI + c);
        } else {
          if (bs < BPS - 1)
            slabV[VIDX(ROWS_PB + slot - 3) + c] =
                aloadf(ghx_sys + (size_t)(bs + 1) * (6 * NXI) + (slot - 3) * NXI + c);
        }
      }
      __syncthreads();
      {
        double pp = 0.0;
#pragma unroll
        for (int k = 0; k < EPT; k++) {
          const int e = tid + k * NTHR;
          const int lr = e / NXI, c = e - lr * NXI;
          const int gr = gr0 + lr;
          const float uc = xreg[k];
          const float um = (gr == 0)       ? uc : slabV[VIDX(lr - 1) + c];
          const float ud = (gr == NXI - 1) ? uc : slabV[VIDX(lr + 1) + c];
          const float ul = (c == 0)        ? uc : slabV[VIDX(lr) + c - 1];
          const float ur = (c == NXI - 1)  ? uc : slabV[VIDX(lr) + c + 1];
          const float pn = mb - (cboo_r[k] * uc + cbmo_r[k] * um + cbom_r[k] * ul + cbop_r[k] * ur + cbpo_r[k] * ud);
          preg[k] = pn; rreg[k] = pn; r0reg[k] = pn;
          slabP[SIDX(lr) + c] = pn;
          slabR[SIDX(lr) + c] = pn;
          pp += (double)pn * (double)pn;
        }
        for (int g = tid; g < 4 * NXI; g += NTHR) {
          const int slot = g / NXI, c = g - slot * NXI;
          if (slot < 2 ? (bs > 0) : (bs < BPS - 1)) {
            const int row = (slot == 0) ? -2 : (slot == 1) ? -1 : (slot == 2) ? ROWS_PB : ROWS_PB + 1;
            float c5[5];
            coef5(Vb, M1b, M2b, gr0 + row, c, c5);
            const float uc = slabV[VIDX(row) + c];
            const float um = slabV[VIDX(row - 1) + c];
            const float ud = slabV[VIDX(row + 1) + c];
            const float ul = (c == 0)       ? uc : slabV[VIDX(row) + c - 1];
            const float ur = (c == NXI - 1) ? uc : slabV[VIDX(row) + c + 1];
            const float pn = mb - (c5[0] * uc + c5[1] * um + c5[2] * ul + c5[3] * ur + c5[4] * ud);
            slabP[SIDX(row) + c] = pn;
            slabR[SIDX(row) + c] = pn;
          }
        }
        bredN(&pp, 1, slots, 15, sys, bs, tid);
      }
      sys_bar(flags, &bphase, tid, bs);  // R2
      if (tid < 64) {
        double sp[1]; shredN(slots, 15, 1, sys, lane, sp);
        const float ra2 = froguard(sp[0]);
        if (lane == 0) { bcf[3] = ra2; sh_r0abs = ra2; }
      }
      continue;
    }

    const float alpha = bcf[0];
    if (code == 2) {
      // C3: x += alpha*p ; r = s (terminal: top breaks next round)
#pragma unroll
      for (int k = 0; k < EPT; k++) {
        const int e = tid + k * NTHR;
        const int lr = e / NXI, c = e - lr * NXI;
        xreg[k] = xreg[k] + alpha * preg[k];
        rreg[k] = rreg[k] - alpha * slabV[VIDX(lr) + c];
      }
      continue;
    }

    // ==== E: full update (v,u,w from LDS; t = u - alpha*w) + ghost reconstruction ====
    {
      const float omega = bcf[1];
      const float beta  = bcf[2];
#pragma unroll
      for (int k = 0; k < EPT; k++) {
        const int e = tid + k * NTHR;
        const int lr = e / NXI, c = e - lr * NXI;
        const float vc = slabV[VIDX(lr) + c];
        const float uu = slabU[lr * NXI + c];
        const float ww = slabW[lr * NXI + c];
        const float sc = rreg[k] - alpha * vc;
        const float tv = uu - alpha * ww;
        xreg[k] = xreg[k] + alpha * preg[k] + omega * sc;
        const float rn = sc - omega * tv;
        const float pn = rn + beta * (preg[k] - omega * vc);
        rreg[k] = rn;
        preg[k] = pn;
        slabP[SIDX(lr) + c] = pn;
        slabR[SIDX(lr) + c] = rn;
      }
      // ghost rows -2,-1,12,13: bit-identical reconstruction of neighbors' updates
      for (int g = tid; g < 4 * NXI; g += NTHR) {
        const int slot = g / NXI, c = g - slot * NXI;
        if (slot < 2 ? (bs > 0) : (bs < BPS - 1)) {
          const int row = (slot == 0) ? -2 : (slot == 1) ? -1 : (slot == 2) ? ROWS_PB : ROWS_PB + 1;
          const int si = SIDX(row) + c;
          const float vg = ghV[g], ug = ghU[g], wg = ghW[g];
          const float rold = slabR[si], pold = slabP[si];
          const float sg = rold - alpha * vg;
          const float tg = ug - alpha * wg;
          const float rn = sg - omega * tg;
          const float pn = rn + beta * (pold - omega * vg);
          slabR[si] = rn;
          slabP[si] = pn;
        }
      }
    }
    // no barrier: next A reads only block-local LDS (loop-top syncthreads)
  }

  // final write-out of x
#pragma unroll
  for (int k = 0; k < EPT; k++) {
    xs[tid + k * NTHR] = xreg[k];
  }
}

extern "C" void kernel_launch(void* const* d_in, const int* in_sizes, int n_in,
                              void* d_out, int out_size, void* d_ws, size_t ws_size,
                              hipStream_t stream) {
  const float* V  = (const float*)d_in[0];
  const float* M1 = (const float*)d_in[1];
  const float* M2 = (const float*)d_in[2];
  float* xout = (float*)d_out;
  float* wsf  = (float*)d_ws;
  hipMemsetAsync(d_ws, 0, 4096, stream);
  bicg_kernel<<<dim3(NBLK), dim3(NTHR), 0, stream>>>(V, M1, M2, xout, wsf);
}

// Round 8
// 451.779 us; speedup vs baseline: 1.6195x; 1.6195x over previous
//
#include <hip/hip_runtime.h>

#define NXI 384
#define NG  (NXI*NXI)          // 147456 elements per system
#define NSYS 8
#define BPS 32                 // blocks per system
#define NBLK (NSYS*BPS)        // 256 blocks
#define NTHR 512               // proven geometry: 128 VGPR, zero spill
#define ROWS_PB 12             // rows per block
#define EPB (ROWS_PB*NXI)      // 4608 elements per block
#define EPT (EPB/NTHR)         // 9 elements per thread

// thr = EPS*NX*NY = 1e-9*147456
#define THRC 1.47456e-4f

// ---- relaxed agent-scope accessors ----
__device__ __forceinline__ float aloadf(const float* p) {
  return __hip_atomic_load(p, __ATOMIC_RELAXED, __HIP_MEMORY_SCOPE_AGENT);
}
__device__ __forceinline__ void astoref(float* p, float v) {
  __hip_atomic_store(p, v, __ATOMIC_RELAXED, __HIP_MEMORY_SCOPE_AGENT);
}
__device__ __forceinline__ double aloadd(const double* p) {
  return __hip_atomic_load(p, __ATOMIC_RELAXED, __HIP_MEMORY_SCOPE_AGENT);
}
__device__ __forceinline__ void astored(double* p, double v) {
  __hip_atomic_store(p, v, __ATOMIC_RELAXED, __HIP_MEMORY_SCOPE_AGENT);
}

__device__ __forceinline__ double wave_red(double v) {
#pragma unroll
  for (int off = 32; off > 0; off >>= 1) v += __shfl_down(v, off, 64);
  return v;
}

// ---- per-system flag barrier (validated protocol) with poll-storm reduction:
// each of 32 lanes polls only ITS OWN flag and latches done (stops loading once
// seen); sleep 4 (~256cy) instead of 1. Cuts steady-state LLC poll loads ~16x
// so the straggler's slot/flag stores aren't contending with the poll storm.
__device__ __forceinline__ void sys_bar(unsigned* flags, unsigned* phase, int tid, int bs) {
  __atomic_signal_fence(__ATOMIC_SEQ_CST);
  __builtin_amdgcn_s_waitcnt(0);
  __syncthreads();
  const unsigned ph = ++(*phase);
  if (tid == 0) {
    __hip_atomic_store(flags + bs, ph, __ATOMIC_RELAXED, __HIP_MEMORY_SCOPE_AGENT);
  }
  if (tid < 64) {
    bool done = (tid >= BPS);       // lanes 32..63 don't poll
    while (true) {
      if (!done) {
        const unsigned f = __hip_atomic_load(flags + tid, __ATOMIC_RELAXED,
                                             __HIP_MEMORY_SCOPE_AGENT);
        done = (f >= ph);
      }
      if (__ballot(done) == ~0ull) break;
      __builtin_amdgcn_s_sleep(4);
    }
  }
  __syncthreads();
  __atomic_signal_fence(__ATOMIC_SEQ_CST);
}

// Block-reduce n<=5 doubles, agent-store to channels [chan0..][sys][bs].
// Cross-wave finish parallelized: lane q sums channel q (same order as the old
// tid0 loop -> bit-identical) and issues its own store, shortening the critical
// path from last wave-arrival to slot-store by ~5x.
__device__ __forceinline__ void bredN(const double* v, int n,
                                      double* slots, int chan0,
                                      int sys, int bs, int tid) {
  __shared__ double sred[NTHR/64][5];
  const int wid = tid >> 6, lane = tid & 63;
#pragma unroll
  for (int q = 0; q < n; q++) {
    const double w = wave_red(v[q]);
    if (lane == 0) sred[wid][q] = w;
  }
  __syncthreads();
  if (tid < n) {
    double a = 0.0;
#pragma unroll
    for (int w2 = 0; w2 < NTHR/64; w2++) a += sred[w2][tid];
    astored(slots + (size_t)(chan0 + tid) * NBLK + sys * BPS + bs, a);
  }
  __syncthreads();
}

// Butterfly sums of n channels (bit-exact identical in every lane/block).
__device__ __forceinline__ void shredN(const double* slots, int chan0, int n,
                                       int sys, int lane, double* out) {
  double v[5];
#pragma unroll
  for (int q = 0; q < n; q++)
    v[q] = aloadd(slots + (size_t)(chan0 + q) * NBLK + sys * BPS + (lane & 31));
#pragma unroll
  for (int q = 0; q < n; q++) {
    double x = v[q];
    x += __shfl_xor(x, 1, 64);
    x += __shfl_xor(x, 2, 64);
    x += __shfl_xor(x, 4, 64);
    x += __shfl_xor(x, 8, 64);
    x += __shfl_xor(x, 16, 64);
    out[q] = x;
  }
}

__device__ __forceinline__ float froguard(double sq) {
  return sq > 0.0 ? (float)sqrt(sq) : 0.0f;
}

// Compute the 5 stencil coefficients at global (row i, col j).
// c5: 0=boo 1=bmo 2=bom 3=bop 4=bpo
__device__ __forceinline__ void coef5(const float* __restrict__ Vb,
                                      const float* __restrict__ M1b,
                                      const float* __restrict__ M2b,
                                      int i, int j, float* c5) {
  const int a0 = (i - 1 < 0) ? 0 : i - 1;
  const int a2 = (i + 1 > NXI - 1) ? NXI - 1 : i + 1;
  const int b0 = (j - 1 < 0) ? 0 : j - 1;
  const int b2 = (j + 1 > NXI - 1) ? NXI - 1 : j + 1;
  const float vc = Vb[j * NXI + i] + 1.0f;
  const float vu = Vb[j * NXI + a0] + 1.0f;
  const float vd = Vb[j * NXI + a2] + 1.0f;
  const float vl = Vb[b0 * NXI + i] + 1.0f;
  const float vr = Vb[b2 * NXI + i] + 1.0f;
  const float D1A = M1b[j * NXI + i] * ((vd - vc) / (0.5f * (vd + vc)));
  const float D1B = M1b[j * NXI + a0] * ((vc - vu) / (0.5f * (vc + vu)));
  const float D2A = M2b[j * NXI + i] * ((vr - vc) / (0.5f * (vr + vc)));
  const float D2B = M2b[b0 * NXI + i] * ((vc - vl) / (0.5f * (vc + vl)));
  c5[0] = 41.0f - 5.0f * (D1B - D1A) - 5.0f * (D2B - D2A);
  c5[1] = -10.0f - 5.0f * D1B;
  c5[2] = -10.0f - 5.0f * D2B;
  c5[3] = -10.0f + 5.0f * D2A;
  c5[4] = -10.0f + 5.0f * D1A;
}

__global__ __launch_bounds__(NTHR, 1) void bicg_kernel(
    const float* __restrict__ V, const float* __restrict__ M1, const float* __restrict__ M2,
    float* __restrict__ xout, float* __restrict__ wsf) {
  const int blk = blockIdx.x;
  const int sys = blk & (NSYS - 1);
  const int bs  = blk >> 3;
  const int tid = threadIdx.x;
  const int lane = tid & 63;
  const int gr0 = bs * ROWS_PB;

  // ---- LDS (~53 KB): rows -1..12 -> index (r+1)*NXI ----
  __shared__ float slabP[14 * NXI];   // p (own + 1 ghost row/side)
  __shared__ float slabS[14 * NXI];   // s (own + ghost); x staging during restart
  __shared__ float vgh[2 * NXI];      // received v ghosts: [0..NXI)=row -1, rest=row 12
  __shared__ float tgh[2 * NXI];      // received t ghosts
  __shared__ float rgh[2 * NXI];      // maintained r ghosts (recursive, bit-exact)
  __shared__ float bcf[4];            // 0:alpha 1:omega 2:beta 3:r_abs
  __shared__ int   bci[1];            // 0 normal, 1 RES, 2 C3, 3 converged-at-init
  __shared__ float sh_r0abs, sh_rho;
  __shared__ double sh_ss2;

  // ---- workspace (control + boundary rows only) ----
  unsigned* flags = (unsigned*)wsf + sys * 32;      // memset 0 before launch
  double* slots = (double*)(wsf + 1024);            // 11 chans * 256 doubles
  float* ghv_all = wsf + 16384;                     // [sys][bs][2][NXI] v boundary
  float* ght_all = ghv_all + (size_t)NSYS * BPS * 2 * NXI;  // t boundary
  float* ghx_all = ght_all + (size_t)NSYS * BPS * 2 * NXI;  // x boundary (restart)
  float* ghq_all = ghx_all + (size_t)NSYS * BPS * 2 * NXI;  // p boundary (restart)
  float* ghv = ghv_all + (size_t)sys * BPS * 2 * NXI;
  float* ght = ght_all + (size_t)sys * BPS * 2 * NXI;
  float* ghx = ghx_all + (size_t)sys * BPS * 2 * NXI;
  float* ghq = ghq_all + (size_t)sys * BPS * 2 * NXI;
  float* ghv_own = ghv + (size_t)bs * 2 * NXI;      // [0]=row0, [NXI]=row11
  float* ght_own = ght + (size_t)bs * 2 * NXI;
  float* ghx_own = ghx + (size_t)bs * 2 * NXI;
  float* ghq_own = ghq + (size_t)bs * 2 * NXI;

  unsigned bphase = 0;

  const size_t so = (size_t)sys * NG;
  const float* Vb  = V  + so;
  const float* M1b = M1 + so;
  const float* M2b = M2 + so;
  float* xs = xout + so + (size_t)bs * EPB;

  // ---------- Phase 0: own-element coeffs -> REGISTERS + V-mean partial ----------
  float cboo_r[EPT], cbmo_r[EPT], cbom_r[EPT], cbop_r[EPT], cbpo_r[EPT];
#pragma unroll
  for (int k = 0; k < EPT; k++) {
    const int e = tid + k * NTHR;
    const int lr = e / NXI, c = e - lr * NXI;
    float c5[5];
    coef5(Vb, M1b, M2b, gr0 + lr, c, c5);
    cboo_r[k] = c5[0]; cbmo_r[k] = c5[1]; cbom_r[k] = c5[2];
    cbop_r[k] = c5[3]; cbpo_r[k] = c5[4];
  }
  {
    double vsum = 0.0;
#pragma unroll
    for (int k = 0; k < EPT; k++) vsum += (double)Vb[bs * EPB + tid + k * NTHR];
    bredN(&vsum, 1, slots, 9, sys, bs, tid);
  }
  sys_bar(flags, &bphase, tid, bs);  // S0 (only setup barrier)

  // ---------- Init: x=mb; p=r=r0 = mb - rowsum*mb on own AND ghost rows ----------
  double smb[1]; shredN(slots, 9, 1, sys, lane, smb);
  const float mb = (float)(smb[0] / (double)NG) + 1.0f;
  float preg[EPT], rreg[EPT], r0reg[EPT], vreg[EPT], treg[EPT], xreg[EPT];
#pragma unroll
  for (int k = 0; k < EPT; k++) {
    const int e = tid + k * NTHR;
    const int ce = e + NXI;
    const float ax = (cboo_r[k] + cbmo_r[k] + cbom_r[k] + cbop_r[k] + cbpo_r[k]) * mb;
    const float pn = mb - ax;
    xreg[k] = mb;
    preg[k] = pn; rreg[k] = pn; r0reg[k] = pn;
    slabP[ce] = pn;
  }
  for (int g = tid; g < 2 * NXI; g += NTHR) {
    const bool top = g < NXI;
    if (top ? (bs > 0) : (bs < BPS - 1)) {
      const int c = top ? g : g - NXI;
      const int ci = top ? c : 13 * NXI + c;     // row -1 / row 12 index
      const int gi = top ? gr0 - 1 : gr0 + ROWS_PB;
      float c5[5];
      coef5(Vb, M1b, M2b, gi, c, c5);            // one-time ghost coeff recompute
      const float pn = mb - (c5[0] + c5[1] + c5[2] + c5[3] + c5[4]) * mb;
      slabP[ci] = pn;
      rgh[g] = pn;
    }
  }
  if (tid == 0) { bcf[3] = 1.0f; bci[0] = 0; }

  for (int it = 0; it < 30; ++it) {
    __syncthreads();                 // bcf/slab writes visible
    if (!(bcf[3] > THRC)) break;     // uniform within system

    // ==== P1: v = A p own rows; publish v rows 0/11; 5 dots ====
    {
      double d[5] = {0, 0, 0, 0, 0};
#pragma unroll
      for (int k = 0; k < EPT; k++) {
        const int e = tid + k * NTHR;
        const int lr = e / NXI, c = e - lr * NXI;
        const int gr = gr0 + lr;
        const int ce = e + NXI;
        const float uc = preg[k];
        const float um = (gr == 0)       ? uc : slabP[ce - NXI];
        const float ud = (gr == NXI - 1) ? uc : slabP[ce + NXI];
        const float ul = (c == 0)        ? uc : slabP[ce - 1];
        const float ur = (c == NXI - 1)  ? uc : slabP[ce + 1];
        const float vv = cboo_r[k] * uc + cbmo_r[k] * um + cbom_r[k] * ul + cbop_r[k] * ur + cbpo_r[k] * ud;
        vreg[k] = vv;
        if (lr == 0)  astoref(ghv_own + c, vv);
        if (lr == 11) astoref(ghv_own + NXI + c, vv);
        d[0] += (double)vv * (double)r0reg[k];      // sigma
        d[1] += (double)vv * (double)vv;            // <v,v>
        d[2] += (double)rreg[k] * (double)r0reg[k]; // rho
        d[3] += (double)rreg[k] * (double)vv;       // <r,v>
        d[4] += (double)rreg[k] * (double)rreg[k];  // <r,r>
      }
      bredN(d, 5, slots, 0, sys, bs, tid);
    }
    sys_bar(flags, &bphase, tid, bs);  // B

    // ==== P2: wave0 scalars || waves1-7 receive v ghosts; then branch ====
    if (tid < 64) {
      double s[5];
      shredN(slots, 0, 5, sys, lane, s);
      const float sigma = (float)s[0];
      const float v_abs = froguard(s[1]);
      const float rho_l = (float)s[2];
      const float r0a = (it == 0) ? froguard(s[4]) : sh_r0abs;
      int code = 0;
      float al = 0.f, ra = 0.f;
      double ss2 = 0.0;
      if (it == 0 && !(r0a > THRC)) {
        code = 3; ra = r0a;
      } else if (sigma <= 1e-9f * v_abs * r0a) {
        code = 1;
      } else {
        al = rho_l / sigma;
        const double da = (double)al;
        ss2 = s[4] - 2.0 * da * s[3] + da * da * s[1];   // <s,s> analytic
        const float s_abs = froguard(ss2);
        if (s_abs <= THRC) { code = 2; ra = s_abs; }
      }
      if (lane == 0) {
        bci[0] = code; bcf[0] = al;
        if (code == 2 || code == 3) bcf[3] = ra;
        sh_ss2 = ss2; sh_rho = rho_l;
        if (it == 0) sh_r0abs = r0a;
      }
    } else {
      for (int g = tid - 64; g < 2 * NXI; g += NTHR - 64) {
        const bool top = g < NXI;
        const int c = top ? g : g - NXI;
        if (top) { if (bs > 0)       vgh[g] = aloadf(ghv + (size_t)(bs - 1) * 2 * NXI + NXI + c); }
        else     { if (bs < BPS - 1) vgh[g] = aloadf(ghv + (size_t)(bs + 1) * 2 * NXI + c); }
      }
    }
    __syncthreads();
    const int code = bci[0];

    if (code == 3) continue;          // converged at init: x stays mb; top breaks

    if (code == 1) {
      // ---- restart: p = r = r0 = mb - A x (explicit 1-row exchanges) ----
#pragma unroll
      for (int k = 0; k < EPT; k++) {
        const int e = tid + k * NTHR;
        const int lr = e / NXI, c = e - lr * NXI;
        slabS[e + NXI] = xreg[k];
        if (lr == 0)  astoref(ghx_own + c, xreg[k]);
        if (lr == 11) astoref(ghx_own + NXI + c, xreg[k]);
      }
      sys_bar(flags, &bphase, tid, bs);  // R1
      for (int g = tid; g < 2 * NXI; g += NTHR) {
        const bool top = g < NXI;
        const int c = top ? g : g - NXI;
        if (top) { if (bs > 0)       slabS[c]            = aloadf(ghx + (size_t)(bs - 1) * 2 * NXI + NXI + c); }
        else     { if (bs < BPS - 1) slabS[13 * NXI + c] = aloadf(ghx + (size_t)(bs + 1) * 2 * NXI + c); }
      }
      __syncthreads();
#pragma unroll
      for (int k = 0; k < EPT; k++) {
        const int e = tid + k * NTHR;
        const int lr = e / NXI, c = e - lr * NXI;
        const int gr = gr0 + lr;
        const int ce = e + NXI;
        const float uc = xreg[k];
        const float um = (gr == 0)       ? uc : slabS[ce - NXI];
        const float ud = (gr == NXI - 1) ? uc : slabS[ce + NXI];
        const float ul = (c == 0)        ? uc : slabS[ce - 1];
        const float ur = (c == NXI - 1)  ? uc : slabS[ce + 1];
        treg[k] = mb - (cboo_r[k] * uc + cbmo_r[k] * um + cbom_r[k] * ul + cbop_r[k] * ur + cbpo_r[k] * ud);
      }
      __syncthreads();  // all x reads done
      {
        double pp = 0;
#pragma unroll
        for (int k = 0; k < EPT; k++) {
          const int e = tid + k * NTHR;
          const int lr = e / NXI, c = e - lr * NXI;
          const float pn = treg[k];
          preg[k] = pn; rreg[k] = pn; r0reg[k] = pn;
          slabP[e + NXI] = pn;
          if (lr == 0)  astoref(ghq_own + c, pn);
          if (lr == 11) astoref(ghq_own + NXI + c, pn);
          pp += (double)pn * (double)pn;
        }
        bredN(&pp, 1, slots, 10, sys, bs, tid);
      }
      sys_bar(flags, &bphase, tid, bs);  // R2
      if (tid < 64) {
        double sp[1]; shredN(slots, 10, 1, sys, lane, sp);
        const float ra = froguard(sp[0]);
        if (lane == 0) { bcf[3] = ra; sh_r0abs = ra; }
      } else {
        for (int g = tid - 64; g < 2 * NXI; g += NTHR - 64) {
          const bool top = g < NXI;
          const int c = top ? g : g - NXI;
          const int ci = top ? c : 13 * NXI + c;
          if (top ? (bs > 0) : (bs < BPS - 1)) {
            const float pn = top ? aloadf(ghq + (size_t)(bs - 1) * 2 * NXI + NXI + c)
                                 : aloadf(ghq + (size_t)(bs + 1) * 2 * NXI + c);
            slabP[ci] = pn;
            rgh[g] = pn;
          }
        }
      }
      continue;   // loop-top syncthreads publishes bcf + slabs
    }

    const float alpha = bcf[0];
    if (code == 2) {
      // C3: x += alpha*p ; r = s (terminal: top breaks next round)
#pragma unroll
      for (int k = 0; k < EPT; k++) {
        xreg[k] = xreg[k] + alpha * preg[k];
        rreg[k] = rreg[k] - alpha * vreg[k];
      }
      continue;
    }

    // ---- s -> slabS (own rows + ghost rows from rgh - alpha*vgh) ----
#pragma unroll
    for (int k = 0; k < EPT; k++) {
      const int e = tid + k * NTHR;
      slabS[e + NXI] = rreg[k] - alpha * vreg[k];
    }
    for (int g = tid; g < 2 * NXI; g += NTHR) {
      const bool top = g < NXI;
      if (top ? (bs > 0) : (bs < BPS - 1)) {
        const int c = top ? g : g - NXI;
        const int ci = top ? c : 13 * NXI + c;
        slabS[ci] = rgh[g] - alpha * vgh[g];
      }
    }
    __syncthreads();
    // ---- t = A s ; publish t rows 0/11 ; 4 dots ----
    {
      double d[4] = {0, 0, 0, 0};
#pragma unroll
      for (int k = 0; k < EPT; k++) {
        const int e = tid + k * NTHR;
        const int lr = e / NXI, c = e - lr * NXI;
        const int gr = gr0 + lr;
        const int ce = e + NXI;
        const float sc = rreg[k] - alpha * vreg[k];
        const float um = (gr == 0)       ? sc : slabS[ce - NXI];
        const float ud = (gr == NXI - 1) ? sc : slabS[ce + NXI];
        const float ul = (c == 0)        ? sc : slabS[ce - 1];
        const float ur = (c == NXI - 1)  ? sc : slabS[ce + 1];
        const float tv = cboo_r[k] * sc + cbmo_r[k] * um + cbom_r[k] * ul + cbop_r[k] * ur + cbpo_r[k] * ud;
        treg[k] = tv;
        if (lr == 0)  astoref(ght_own + c, tv);
        if (lr == 11) astoref(ght_own + NXI + c, tv);
        d[0] += (double)tv * (double)tv;          // <t,t>
        d[1] += (double)tv * (double)sc;          // <t,s>
        d[2] += (double)sc * (double)r0reg[k];    // <s,r0>
        d[3] += (double)tv * (double)r0reg[k];    // <t,r0>
      }
      bredN(d, 4, slots, 5, sys, bs, tid);
    }
    sys_bar(flags, &bphase, tid, bs);  // C

    // ==== P3: wave0 scalars || waves1-7 receive t ghosts; then update ====
    if (tid < 64) {
      double s2[4];
      shredN(slots, 5, 4, sys, lane, s2);
      const double tt = s2[0], ts = s2[1], sr0 = s2[2], tr0 = s2[3];
      const float om = (float)ts / (float)tt;
      const double dw = (double)om;
      const float rho_new = (float)(sr0 - dw * tr0);
      const double rr_new = sh_ss2 - 2.0 * dw * ts + dw * dw * tt;
      const float be = (bcf[0] / om) * (rho_new / sh_rho);
      if (lane == 0) {
        bcf[1] = om; bcf[2] = be; bcf[3] = froguard(rr_new);
      }
    } else {
      for (int g = tid - 64; g < 2 * NXI; g += NTHR - 64) {
        const bool top = g < NXI;
        const int c = top ? g : g - NXI;
        if (top) { if (bs > 0)       tgh[g] = aloadf(ght + (size_t)(bs - 1) * 2 * NXI + NXI + c); }
        else     { if (bs < BPS - 1) tgh[g] = aloadf(ght + (size_t)(bs + 1) * 2 * NXI + c); }
      }
    }
    __syncthreads();
    {
      const float omega = bcf[1];
      const float beta  = bcf[2];
#pragma unroll
      for (int k = 0; k < EPT; k++) {
        const int e = tid + k * NTHR;
        const float sc = rreg[k] - alpha * vreg[k];
        xreg[k] = xreg[k] + alpha * preg[k] + omega * sc;
        const float rn = sc - omega * treg[k];
        const float pn = rn + beta * (preg[k] - omega * vreg[k]);
        rreg[k] = rn;
        preg[k] = pn;
        slabP[e + NXI] = pn;
      }
      // ghost maintenance (rows -1, 12): bit-identical to neighbors' own rows
      for (int g = tid; g < 2 * NXI; g += NTHR) {
        const bool top = g < NXI;
        if (top ? (bs > 0) : (bs < BPS - 1)) {
          const int c = top ? g : g - NXI;
          const int ci = top ? c : 13 * NXI + c;
          const float sg = slabS[ci];
          const float rg_new = sg - omega * tgh[g];
          const float pg_new = rg_new + beta * (slabP[ci] - omega * vgh[g]);
          rgh[g] = rg_new;
          slabP[ci] = pg_new;
        }
      }
    }
    // no barrier: next P1 reads only block-local LDS (loop-top syncthreads)
  }

  // final write-out of x
#pragma unroll
  for (int k = 0; k < EPT; k++) {
    xs[tid + k * NTHR] = xreg[k];
  }
}

extern "C" void kernel_launch(void* const* d_in, const int* in_sizes, int n_in,
                              void* d_out, int out_size, void* d_ws, size_t ws_size,
                              hipStream_t stream) {
  const float* V  = (const float*)d_in[0];
  const float* M1 = (const float*)d_in[1];
  const float* M2 = (const float*)d_in[2];
  float* xout = (float*)d_out;
  float* wsf  = (float*)d_ws;
  hipMemsetAsync(d_ws, 0, 4096, stream);
  bicg_kernel<<<dim3(NBLK), dim3(NTHR), 0, stream>>>(V, M1, M2, xout, wsf);
}

// Round 9
// 431.271 us; speedup vs baseline: 1.6965x; 1.0476x over previous
//
#include <hip/hip_runtime.h>

#define NXI 384
#define NG  (NXI*NXI)          // 147456 elements per system
#define NSYS 8
#define BPS 32                 // blocks per system
#define NBLK (NSYS*BPS)        // 256 blocks
#define NTHR 512               // proven geometry: 128 VGPR, zero spill
#define ROWS_PB 12             // rows per block
#define EPB (ROWS_PB*NXI)      // 4608 elements per block
#define EPT (EPB/NTHR)         // 9 elements per thread

// thr = EPS*NX*NY = 1e-9*147456
#define THRC 1.47456e-4f

// ---- workspace layout (all blocks' barrier state in PRIVATE cache lines) ----
// bytes [0, 16K):  flags — one 64B line per block: flag(sys,bs) at u32 index (sys*BPS+bs)*16
// bytes [16K,48K): slots — one 128B record per block: rec(sys,bs)[16 doubles], channel=idx
// bytes [48K,...): ghost rows (v,t,x,p boundary exchanges)

// ---- relaxed agent-scope accessors ----
__device__ __forceinline__ float aloadf(const float* p) {
  return __hip_atomic_load(p, __ATOMIC_RELAXED, __HIP_MEMORY_SCOPE_AGENT);
}
__device__ __forceinline__ void astoref(float* p, float v) {
  __hip_atomic_store(p, v, __ATOMIC_RELAXED, __HIP_MEMORY_SCOPE_AGENT);
}
__device__ __forceinline__ double aloadd(const double* p) {
  return __hip_atomic_load(p, __ATOMIC_RELAXED, __HIP_MEMORY_SCOPE_AGENT);
}
__device__ __forceinline__ void astored(double* p, double v) {
  __hip_atomic_store(p, v, __ATOMIC_RELAXED, __HIP_MEMORY_SCOPE_AGENT);
}

__device__ __forceinline__ double wave_red(double v) {
#pragma unroll
  for (int off = 32; off > 0; off >>= 1) v += __shfl_down(v, off, 64);
  return v;
}

// ---- per-system flag barrier (validated protocol; R8 sticky poll) ----
// Flags now 64B-padded: block's flag store touches ONLY its own LLC line
// (was: 16 blocks per line -> cross-XCD store serialization on the hot path).
__device__ __forceinline__ void sys_bar(unsigned* flags, unsigned* phase, int tid, int bs) {
  __atomic_signal_fence(__ATOMIC_SEQ_CST);
  __builtin_amdgcn_s_waitcnt(0);
  __syncthreads();
  const unsigned ph = ++(*phase);
  if (tid == 0) {
    __hip_atomic_store(flags + (size_t)bs * 16, ph, __ATOMIC_RELAXED, __HIP_MEMORY_SCOPE_AGENT);
  }
  if (tid < 64) {
    bool done = false;
    while (true) {
      if (!done) {
        const unsigned f = __hip_atomic_load(flags + (size_t)(tid & 31) * 16,
                                             __ATOMIC_RELAXED, __HIP_MEMORY_SCOPE_AGENT);
        done = (f >= ph);
      }
      if (__ballot(done) == ~0ull) break;
      __builtin_amdgcn_s_sleep(2);
    }
  }
  __syncthreads();
  __atomic_signal_fence(__ATOMIC_SEQ_CST);
}

// Block-reduce n<=5 doubles into this block's PRIVATE 128B slot record.
// Channel q -> record word (chan0+q). Lane q sums channel q (same order as the
// original tid0 loop -> bit-identical). No trailing syncthreads: every call
// site is immediately followed by sys_bar (waitcnt+barrier supply the guard;
// all slot stores are wave0's, drained by wave0's s_waitcnt before flag store).
__device__ __forceinline__ void bredN(const double* v, int n,
                                      double* slots, int chan0,
                                      int sys, int bs, int tid) {
  __shared__ double sred[NTHR/64][5];
  const int wid = tid >> 6, lane = tid & 63;
#pragma unroll
  for (int q = 0; q < n; q++) {
    const double w = wave_red(v[q]);
    if (lane == 0) sred[wid][q] = w;
  }
  __syncthreads();
  if (tid < n) {
    double a = 0.0;
#pragma unroll
    for (int w2 = 0; w2 < NTHR/64; w2++) a += sred[w2][tid];
    astored(slots + (size_t)(sys * BPS + bs) * 16 + (chan0 + tid), a);
  }
}

// Butterfly sums of n channels (bit-exact identical in every lane/block).
__device__ __forceinline__ void shredN(const double* slots, int chan0, int n,
                                       int sys, int lane, double* out) {
  double v[5];
#pragma unroll
  for (int q = 0; q < n; q++)
    v[q] = aloadd(slots + (size_t)(sys * BPS + (lane & 31)) * 16 + (chan0 + q));
#pragma unroll
  for (int q = 0; q < n; q++) {
    double x = v[q];
    x += __shfl_xor(x, 1, 64);
    x += __shfl_xor(x, 2, 64);
    x += __shfl_xor(x, 4, 64);
    x += __shfl_xor(x, 8, 64);
    x += __shfl_xor(x, 16, 64);
    out[q] = x;
  }
}

__device__ __forceinline__ float froguard(double sq) {
  return sq > 0.0 ? (float)sqrt(sq) : 0.0f;
}

// Compute the 5 stencil coefficients at global (row i, col j).
// c5: 0=boo 1=bmo 2=bom 3=bop 4=bpo
__device__ __forceinline__ void coef5(const float* __restrict__ Vb,
                                      const float* __restrict__ M1b,
                                      const float* __restrict__ M2b,
                                      int i, int j, float* c5) {
  const int a0 = (i - 1 < 0) ? 0 : i - 1;
  const int a2 = (i + 1 > NXI - 1) ? NXI - 1 : i + 1;
  const int b0 = (j - 1 < 0) ? 0 : j - 1;
  const int b2 = (j + 1 > NXI - 1) ? NXI - 1 : j + 1;
  const float vc = Vb[j * NXI + i] + 1.0f;
  const float vu = Vb[j * NXI + a0] + 1.0f;
  const float vd = Vb[j * NXI + a2] + 1.0f;
  const float vl = Vb[b0 * NXI + i] + 1.0f;
  const float vr = Vb[b2 * NXI + i] + 1.0f;
  const float D1A = M1b[j * NXI + i] * ((vd - vc) / (0.5f * (vd + vc)));
  const float D1B = M1b[j * NXI + a0] * ((vc - vu) / (0.5f * (vc + vu)));
  const float D2A = M2b[j * NXI + i] * ((vr - vc) / (0.5f * (vr + vc)));
  const float D2B = M2b[b0 * NXI + i] * ((vc - vl) / (0.5f * (vc + vl)));
  c5[0] = 41.0f - 5.0f * (D1B - D1A) - 5.0f * (D2B - D2A);
  c5[1] = -10.0f - 5.0f * D1B;
  c5[2] = -10.0f - 5.0f * D2B;
  c5[3] = -10.0f + 5.0f * D2A;
  c5[4] = -10.0f + 5.0f * D1A;
}

__global__ __launch_bounds__(NTHR, 1) void bicg_kernel(
    const float* __restrict__ V, const float* __restrict__ M1, const float* __restrict__ M2,
    float* __restrict__ xout, float* __restrict__ wsf) {
  const int blk = blockIdx.x;
  const int sys = blk & (NSYS - 1);
  const int bs  = blk >> 3;
  const int tid = threadIdx.x;
  const int lane = tid & 63;
  const int gr0 = bs * ROWS_PB;

  // ---- LDS (~53 KB): rows -1..12 -> index (r+1)*NXI ----
  __shared__ float slabP[14 * NXI];   // p (own + 1 ghost row/side)
  __shared__ float slabS[14 * NXI];   // s (own + ghost); x staging during restart
  __shared__ float vgh[2 * NXI];      // received v ghosts: [0..NXI)=row -1, rest=row 12
  __shared__ float tgh[2 * NXI];      // received t ghosts
  __shared__ float rgh[2 * NXI];      // maintained r ghosts (recursive, bit-exact)
  __shared__ float bcf[4];            // 0:alpha 1:omega 2:beta 3:r_abs
  __shared__ int   bci[1];            // 0 normal, 1 RES, 2 C3, 3 converged-at-init
  __shared__ float sh_r0abs, sh_rho;
  __shared__ double sh_ss2;

  // ---- workspace (private-line layout; see header comment) ----
  unsigned* flags = (unsigned*)wsf + (size_t)sys * BPS * 16;  // 64B per flag
  double* slots = (double*)(wsf + 4096);                      // 128B record per block
  float* ghv_all = wsf + 12288;                               // [sys][bs][2][NXI] v boundary
  float* ght_all = ghv_all + (size_t)NSYS * BPS * 2 * NXI;    // t boundary
  float* ghx_all = ght_all + (size_t)NSYS * BPS * 2 * NXI;    // x boundary (restart)
  float* ghq_all = ghx_all + (size_t)NSYS * BPS * 2 * NXI;    // p boundary (restart)
  float* ghv = ghv_all + (size_t)sys * BPS * 2 * NXI;
  float* ght = ght_all + (size_t)sys * BPS * 2 * NXI;
  float* ghx = ghx_all + (size_t)sys * BPS * 2 * NXI;
  float* ghq = ghq_all + (size_t)sys * BPS * 2 * NXI;
  float* ghv_own = ghv + (size_t)bs * 2 * NXI;      // [0]=row0, [NXI]=row11
  float* ght_own = ght + (size_t)bs * 2 * NXI;
  float* ghx_own = ghx + (size_t)bs * 2 * NXI;
  float* ghq_own = ghq + (size_t)bs * 2 * NXI;

  unsigned bphase = 0;

  const size_t so = (size_t)sys * NG;
  const float* Vb  = V  + so;
  const float* M1b = M1 + so;
  const float* M2b = M2 + so;
  float* xs = xout + so + (size_t)bs * EPB;

  // ---------- Phase 0: own-element coeffs -> REGISTERS + V-mean partial ----------
  float cboo_r[EPT], cbmo_r[EPT], cbom_r[EPT], cbop_r[EPT], cbpo_r[EPT];
#pragma unroll
  for (int k = 0; k < EPT; k++) {
    const int e = tid + k * NTHR;
    const int lr = e / NXI, c = e - lr * NXI;
    float c5[5];
    coef5(Vb, M1b, M2b, gr0 + lr, c, c5);
    cboo_r[k] = c5[0]; cbmo_r[k] = c5[1]; cbom_r[k] = c5[2];
    cbop_r[k] = c5[3]; cbpo_r[k] = c5[4];
  }
  {
    double vsum = 0.0;
#pragma unroll
    for (int k = 0; k < EPT; k++) vsum += (double)Vb[bs * EPB + tid + k * NTHR];
    bredN(&vsum, 1, slots, 9, sys, bs, tid);
  }
  sys_bar(flags, &bphase, tid, bs);  // S0 (only setup barrier)

  // ---------- Init: x=mb; p=r=r0 = mb - rowsum*mb on own AND ghost rows ----------
  double smb[1]; shredN(slots, 9, 1, sys, lane, smb);
  const float mb = (float)(smb[0] / (double)NG) + 1.0f;
  float preg[EPT], rreg[EPT], r0reg[EPT], vreg[EPT], treg[EPT], xreg[EPT];
#pragma unroll
  for (int k = 0; k < EPT; k++) {
    const int e = tid + k * NTHR;
    const int ce = e + NXI;
    const float ax = (cboo_r[k] + cbmo_r[k] + cbom_r[k] + cbop_r[k] + cbpo_r[k]) * mb;
    const float pn = mb - ax;
    xreg[k] = mb;
    preg[k] = pn; rreg[k] = pn; r0reg[k] = pn;
    slabP[ce] = pn;
  }
  for (int g = tid; g < 2 * NXI; g += NTHR) {
    const bool top = g < NXI;
    if (top ? (bs > 0) : (bs < BPS - 1)) {
      const int c = top ? g : g - NXI;
      const int ci = top ? c : 13 * NXI + c;     // row -1 / row 12 index
      const int gi = top ? gr0 - 1 : gr0 + ROWS_PB;
      float c5[5];
      coef5(Vb, M1b, M2b, gi, c, c5);            // one-time ghost coeff recompute
      const float pn = mb - (c5[0] + c5[1] + c5[2] + c5[3] + c5[4]) * mb;
      slabP[ci] = pn;
      rgh[g] = pn;
    }
  }
  if (tid == 0) { bcf[3] = 1.0f; bci[0] = 0; }

  for (int it = 0; it < 30; ++it) {
    __syncthreads();                 // bcf/slab writes visible
    if (!(bcf[3] > THRC)) break;     // uniform within system

    // ==== P1: v = A p own rows; publish v rows 0/11; 5 dots ====
    {
      double d[5] = {0, 0, 0, 0, 0};
#pragma unroll
      for (int k = 0; k < EPT; k++) {
        const int e = tid + k * NTHR;
        const int lr = e / NXI, c = e - lr * NXI;
        const int gr = gr0 + lr;
        const int ce = e + NXI;
        const float uc = preg[k];
        const float um = (gr == 0)       ? uc : slabP[ce - NXI];
        const float ud = (gr == NXI - 1) ? uc : slabP[ce + NXI];
        const float ul = (c == 0)        ? uc : slabP[ce - 1];
        const float ur = (c == NXI - 1)  ? uc : slabP[ce + 1];
        const float vv = cboo_r[k] * uc + cbmo_r[k] * um + cbom_r[k] * ul + cbop_r[k] * ur + cbpo_r[k] * ud;
        vreg[k] = vv;
        if (lr == 0)  astoref(ghv_own + c, vv);
        if (lr == 11) astoref(ghv_own + NXI + c, vv);
        d[0] += (double)vv * (double)r0reg[k];      // sigma
        d[1] += (double)vv * (double)vv;            // <v,v>
        d[2] += (double)rreg[k] * (double)r0reg[k]; // rho
        d[3] += (double)rreg[k] * (double)vv;       // <r,v>
        d[4] += (double)rreg[k] * (double)rreg[k];  // <r,r>
      }
      bredN(d, 5, slots, 0, sys, bs, tid);
    }
    sys_bar(flags, &bphase, tid, bs);  // B

    // ==== P2: wave0 scalars || waves1-7 receive v ghosts; then branch ====
    if (tid < 64) {
      double s[5];
      shredN(slots, 0, 5, sys, lane, s);
      const float sigma = (float)s[0];
      const float v_abs = froguard(s[1]);
      const float rho_l = (float)s[2];
      const float r0a = (it == 0) ? froguard(s[4]) : sh_r0abs;
      int code = 0;
      float al = 0.f, ra = 0.f;
      double ss2 = 0.0;
      if (it == 0 && !(r0a > THRC)) {
        code = 3; ra = r0a;
      } else if (sigma <= 1e-9f * v_abs * r0a) {
        code = 1;
      } else {
        al = rho_l / sigma;
        const double da = (double)al;
        ss2 = s[4] - 2.0 * da * s[3] + da * da * s[1];   // <s,s> analytic
        const float s_abs = froguard(ss2);
        if (s_abs <= THRC) { code = 2; ra = s_abs; }
      }
      if (lane == 0) {
        bci[0] = code; bcf[0] = al;
        if (code == 2 || code == 3) bcf[3] = ra;
        sh_ss2 = ss2; sh_rho = rho_l;
        if (it == 0) sh_r0abs = r0a;
      }
    } else {
      for (int g = tid - 64; g < 2 * NXI; g += NTHR - 64) {
        const bool top = g < NXI;
        const int c = top ? g : g - NXI;
        if (top) { if (bs > 0)       vgh[g] = aloadf(ghv + (size_t)(bs - 1) * 2 * NXI + NXI + c); }
        else     { if (bs < BPS - 1) vgh[g] = aloadf(ghv + (size_t)(bs + 1) * 2 * NXI + c); }
      }
    }
    __syncthreads();
    const int code = bci[0];

    if (code == 3) continue;          // converged at init: x stays mb; top breaks

    if (code == 1) {
      // ---- restart: p = r = r0 = mb - A x (explicit 1-row exchanges) ----
#pragma unroll
      for (int k = 0; k < EPT; k++) {
        const int e = tid + k * NTHR;
        const int lr = e / NXI, c = e - lr * NXI;
        slabS[e + NXI] = xreg[k];
        if (lr == 0)  astoref(ghx_own + c, xreg[k]);
        if (lr == 11) astoref(ghx_own + NXI + c, xreg[k]);
      }
      sys_bar(flags, &bphase, tid, bs);  // R1
      for (int g = tid; g < 2 * NXI; g += NTHR) {
        const bool top = g < NXI;
        const int c = top ? g : g - NXI;
        if (top) { if (bs > 0)       slabS[c]            = aloadf(ghx + (size_t)(bs - 1) * 2 * NXI + NXI + c); }
        else     { if (bs < BPS - 1) slabS[13 * NXI + c] = aloadf(ghx + (size_t)(bs + 1) * 2 * NXI + c); }
      }
      __syncthreads();
#pragma unroll
      for (int k = 0; k < EPT; k++) {
        const int e = tid + k * NTHR;
        const int lr = e / NXI, c = e - lr * NXI;
        const int gr = gr0 + lr;
        const int ce = e + NXI;
        const float uc = xreg[k];
        const float um = (gr == 0)       ? uc : slabS[ce - NXI];
        const float ud = (gr == NXI - 1) ? uc : slabS[ce + NXI];
        const float ul = (c == 0)        ? uc : slabS[ce - 1];
        const float ur = (c == NXI - 1)  ? uc : slabS[ce + 1];
        treg[k] = mb - (cboo_r[k] * uc + cbmo_r[k] * um + cbom_r[k] * ul + cbop_r[k] * ur + cbpo_r[k] * ud);
      }
      __syncthreads();  // all x reads done
      {
        double pp = 0;
#pragma unroll
        for (int k = 0; k < EPT; k++) {
          const int e = tid + k * NTHR;
          const int lr = e / NXI, c = e - lr * NXI;
          const float pn = treg[k];
          preg[k] = pn; rreg[k] = pn; r0reg[k] = pn;
          slabP[e + NXI] = pn;
          if (lr == 0)  astoref(ghq_own + c, pn);
          if (lr == 11) astoref(ghq_own + NXI + c, pn);
          pp += (double)pn * (double)pn;
        }
        bredN(&pp, 1, slots, 10, sys, bs, tid);
      }
      sys_bar(flags, &bphase, tid, bs);  // R2
      if (tid < 64) {
        double sp[1]; shredN(slots, 10, 1, sys, lane, sp);
        const float ra = froguard(sp[0]);
        if (lane == 0) { bcf[3] = ra; sh_r0abs = ra; }
      } else {
        for (int g = tid - 64; g < 2 * NXI; g += NTHR - 64) {
          const bool top = g < NXI;
          const int c = top ? g : g - NXI;
          const int ci = top ? c : 13 * NXI + c;
          if (top ? (bs > 0) : (bs < BPS - 1)) {
            const float pn = top ? aloadf(ghq + (size_t)(bs - 1) * 2 * NXI + NXI + c)
                                 : aloadf(ghq + (size_t)(bs + 1) * 2 * NXI + c);
            slabP[ci] = pn;
            rgh[g] = pn;
          }
        }
      }
      continue;   // loop-top syncthreads publishes bcf + slabs
    }

    const float alpha = bcf[0];
    if (code == 2) {
      // C3: x += alpha*p ; r = s (terminal: top breaks next round)
#pragma unroll
      for (int k = 0; k < EPT; k++) {
        xreg[k] = xreg[k] + alpha * preg[k];
        rreg[k] = rreg[k] - alpha * vreg[k];
      }
      continue;
    }

    // ---- s -> slabS (own rows + ghost rows from rgh - alpha*vgh) ----
#pragma unroll
    for (int k = 0; k < EPT; k++) {
      const int e = tid + k * NTHR;
      slabS[e + NXI] = rreg[k] - alpha * vreg[k];
    }
    for (int g = tid; g < 2 * NXI; g += NTHR) {
      const bool top = g < NXI;
      if (top ? (bs > 0) : (bs < BPS - 1)) {
        const int c = top ? g : g - NXI;
        const int ci = top ? c : 13 * NXI + c;
        slabS[ci] = rgh[g] - alpha * vgh[g];
      }
    }
    __syncthreads();
    // ---- t = A s ; publish t rows 0/11 ; 4 dots ----
    {
      double d[4] = {0, 0, 0, 0};
#pragma unroll
      for (int k = 0; k < EPT; k++) {
        const int e = tid + k * NTHR;
        const int lr = e / NXI, c = e - lr * NXI;
        const int gr = gr0 + lr;
        const int ce = e + NXI;
        const float sc = rreg[k] - alpha * vreg[k];
        const float um = (gr == 0)       ? sc : slabS[ce - NXI];
        const float ud = (gr == NXI - 1) ? sc : slabS[ce + NXI];
        const float ul = (c == 0)        ? sc : slabS[ce - 1];
        const float ur = (c == NXI - 1)  ? sc : slabS[ce + 1];
        const float tv = cboo_r[k] * sc + cbmo_r[k] * um + cbom_r[k] * ul + cbop_r[k] * ur + cbpo_r[k] * ud;
        treg[k] = tv;
        if (lr == 0)  astoref(ght_own + c, tv);
        if (lr == 11) astoref(ght_own + NXI + c, tv);
        d[0] += (double)tv * (double)tv;          // <t,t>
        d[1] += (double)tv * (double)sc;          // <t,s>
        d[2] += (double)sc * (double)r0reg[k];    // <s,r0>
        d[3] += (double)tv * (double)r0reg[k];    // <t,r0>
      }
      bredN(d, 4, slots, 5, sys, bs, tid);
    }
    sys_bar(flags, &bphase, tid, bs);  // C

    // ==== P3: wave0 scalars || waves1-7 receive t ghosts; then update ====
    if (tid < 64) {
      double s2[4];
      shredN(slots, 5, 4, sys, lane, s2);
      const double tt = s2[0], ts = s2[1], sr0 = s2[2], tr0 = s2[3];
      const float om = (float)ts / (float)tt;
      const double dw = (double)om;
      const float rho_new = (float)(sr0 - dw * tr0);
      const double rr_new = sh_ss2 - 2.0 * dw * ts + dw * dw * tt;
      const float be = (bcf[0] / om) * (rho_new / sh_rho);
      if (lane == 0) {
        bcf[1] = om; bcf[2] = be; bcf[3] = froguard(rr_new);
      }
    } else {
      for (int g = tid - 64; g < 2 * NXI; g += NTHR - 64) {
        const bool top = g < NXI;
        const int c = top ? g : g - NXI;
        if (top) { if (bs > 0)       tgh[g] = aloadf(ght + (size_t)(bs - 1) * 2 * NXI + NXI + c); }
        else     { if (bs < BPS - 1) tgh[g] = aloadf(ght + (size_t)(bs + 1) * 2 * NXI + c); }
      }
    }
    __syncthreads();
    {
      const float omega = bcf[1];
      const float beta  = bcf[2];
#pragma unroll
      for (int k = 0; k < EPT; k++) {
        const int e = tid + k * NTHR;
        const float sc = rreg[k] - alpha * vreg[k];
        xreg[k] = xreg[k] + alpha * preg[k] + omega * sc;
        const float rn = sc - omega * treg[k];
        const float pn = rn + beta * (preg[k] - omega * vreg[k]);
        rreg[k] = rn;
        preg[k] = pn;
        slabP[e + NXI] = pn;
      }
      // ghost maintenance (rows -1, 12): bit-identical to neighbors' own rows
      for (int g = tid; g < 2 * NXI; g += NTHR) {
        const bool top = g < NXI;
        if (top ? (bs > 0) : (bs < BPS - 1)) {
          const int c = top ? g : g - NXI;
          const int ci = top ? c : 13 * NXI + c;
          const float sg = slabS[ci];
          const float rg_new = sg - omega * tgh[g];
          const float pg_new = rg_new + beta * (slabP[ci] - omega * vgh[g]);
          rgh[g] = rg_new;
          slabP[ci] = pg_new;
        }
      }
    }
    // no barrier: next P1 reads only block-local LDS (loop-top syncthreads)
  }

  // final write-out of x
#pragma unroll
  for (int k = 0; k < EPT; k++) {
    xs[tid + k * NTHR] = xreg[k];
  }
}

extern "C" void kernel_launch(void* const* d_in, const int* in_sizes, int n_in,
                              void* d_out, int out_size, void* d_ws, size_t ws_size,
                              hipStream_t stream) {
  const float* V  = (const float*)d_in[0];
  const float* M1 = (const float*)d_in[1];
  const float* M2 = (const float*)d_in[2];
  float* xout = (float*)d_out;
  float* wsf  = (float*)d_ws;
  hipMemsetAsync(d_ws, 0, 65536, stream);   // covers 16K flags + 32K slots
  bicg_kernel<<<dim3(NBLK), dim3(NTHR), 0, stream>>>(V, M1, M2, xout, wsf);
}